// Round 6
// baseline (2929.612 us; speedup 1.0000x reference)
//
#include <hip/hip_runtime.h>

namespace {

constexpr int Hn = 50;    // hidden size
constexpr int Bn = 2048;  // batch
constexpr int Tn = 512;   // sequence length
constexpr int RS = 152;   // A-plane row stride in shorts (76 words = 12 mod 32 -> uniform banks)

typedef short short8 __attribute__((ext_vector_type(8)));
typedef float f32x4 __attribute__((ext_vector_type(4)));

__device__ __forceinline__ unsigned bcu(float f) { return __builtin_bit_cast(unsigned, f); }
__device__ __forceinline__ float bcf(unsigned u) { return __builtin_bit_cast(float, u); }

__device__ __forceinline__ float fsig(float x) {
  return 1.0f / (1.0f + __expf(-x));  // x<<0 -> exp=inf -> 0 : safe
}
__device__ __forceinline__ float ftanh(float x) {
  float a = fabsf(x);
  float e = __expf(-2.0f * a);        // in (0,1]
  float t = (1.0f - e) / (1.0f + e);
  return copysignf(t, x);
}
// split fp32 into bf16 hi + lo, write both LDS planes
__device__ __forceinline__ void wsplit(short* ph, short* pl, float v) {
  const unsigned u = bcu(v);
  *ph = (short)(u >> 16);
  *pl = (short)(bcu(v - bcf(u & 0xFFFF0000u)) >> 16);
}

#define MF(a, b, c) __builtin_amdgcn_mfma_f32_16x16x32_bf16(a, b, c, 0, 0, 0)

// ============================================================================
// Single-barrier MFMA LSTM. Block = 256 thr = 4 waves = 16 batch elems;
// 128 blocks. Wall time = 512 x per-step critical path, so the step is
// minimized:
//  - W rows PERMUTED: n = 4*cell + gate  ->  one 16-wide N-tile holds all 4
//    gates of 4 cells. After MFMA (D: m=quad*4+reg, n=16*tile+nl), a 4-lane
//    x 4-reg shuffle transpose gives each lane all 4 gates of one
//    (cell, elem) -> cell update fully in registers (no s_g LDS round trip,
//    no second barrier).
//  - A-planes (u = [x ; h] split bf16 hi/lo) double-buffered in LDS; the one
//    __syncthreads per step separates next-buffer writes from this-buffer
//    reads. Row stride 76 words = 12 mod 32 -> conflict-free b128 reads.
//  - fp32 accuracy via 3-term split-bf16 (Ah*Bh + Al*Bh + Ah*Bl), split into
//    two 6-deep MFMA chains. Weights persist as B-fragments (AGPR-resident,
//    immune to the R1-R4 demotion/spill pathology; verified R5 VGPR=100).
// ============================================================================

#define LOADB(I, C)                                                         \
  if (NC > (C) && tl##I < 13) {                                             \
    const int cc = 4 * tl##I + jj;                                          \
    _Pragma("unroll") for (int j2 = 0; j2 < 8; ++j2) {                      \
      const int k = (C) * 32 + quad * 8 + j2;                               \
      float wv = 0.f;                                                       \
      if (cc < Hn) {                                                        \
        const int row = ss * Hn + cc;  /* gate ss of cell cc */             \
        if (FIRST) {                                                        \
          if (k == 0) wv = wih[row];                                        \
          else if (k <= Hn) wv = whh[row * Hn + k - 1];                     \
        } else {                                                            \
          if (k < Hn) wv = wih[row * Hn + k];                               \
          else if (k < 2 * Hn) wv = whh[row * Hn + k - Hn];                 \
        }                                                                   \
      }                                                                     \
      const unsigned u = bcu(wv);                                           \
      bh##I##C[j2] = (short)(u >> 16);                                      \
      bl##I##C[j2] = (short)(bcu(wv - bcf(u & 0xFFFF0000u)) >> 16);         \
    }                                                                       \
  }

#define BIASLD(I)                                                           \
  float bI##I = 0.f, bF##I = 0.f, bG##I = 0.f, bO##I = 0.f;                 \
  if (tl##I < 13) {                                                         \
    const int c = 4 * tl##I + jj;                                           \
    if (c < Hn) {                                                           \
      bI##I = bias[c];                                                      \
      bF##I = bias[Hn + c];                                                 \
      bG##I = bias[2 * Hn + c];                                             \
      bO##I = bias[3 * Hn + c];                                             \
    }                                                                       \
  }

#define TILE_STEP(I)                                                        \
  if (tl##I < 13) {                                                         \
    f32x4 ac = {0.f, 0.f, 0.f, 0.f};                                        \
    ac = MF(ah0, bh##I##0, ac);                                             \
    ac = MF(aL0, bh##I##0, ac);                                             \
    ac = MF(ah0, bl##I##0, ac);                                             \
    ac = MF(ah1, bh##I##1, ac);                                             \
    ac = MF(aL1, bh##I##1, ac);                                             \
    ac = MF(ah1, bl##I##1, ac);                                             \
    if (NC > 2) {                                                           \
      f32x4 ac2 = {0.f, 0.f, 0.f, 0.f};                                     \
      ac2 = MF(ah2, bh##I##2, ac2);                                         \
      ac2 = MF(aL2, bh##I##2, ac2);                                         \
      ac2 = MF(ah2, bl##I##2, ac2);                                         \
      ac2 = MF(ah3, bh##I##3, ac2);                                         \
      ac2 = MF(aL3, bh##I##3, ac2);                                         \
      ac2 = MF(ah3, bl##I##3, ac2);                                         \
      ac = ac + ac2;                                                        \
    }                                                                       \
    float v0 = ac[0], v1 = ac[1], v2 = ac[2], v3 = ac[3];                   \
    /* 4x4 transpose across lane-quads: lanes<->regs (gates<->elems) */     \
    {                                                                       \
      const bool sel = (lane & 1) != 0;                                     \
      float e0 = sel ? v0 : v1; e0 = __shfl_xor(e0, 1);                     \
      if (sel) v0 = e0; else v1 = e0;                                       \
      float e1 = sel ? v2 : v3; e1 = __shfl_xor(e1, 1);                     \
      if (sel) v2 = e1; else v3 = e1;                                       \
    }                                                                       \
    {                                                                       \
      const bool sel = (lane & 2) != 0;                                     \
      float e0 = sel ? v0 : v2; e0 = __shfl_xor(e0, 2);                     \
      if (sel) v0 = e0; else v2 = e0;                                       \
      float e1 = sel ? v1 : v3; e1 = __shfl_xor(e1, 2);                     \
      if (sel) v1 = e1; else v3 = e1;                                       \
    }                                                                       \
    const int c = 4 * tl##I + jj;                                           \
    const float I_ = fsig(v0 + bI##I);                                      \
    const float F_ = fsig(v1 + bF##I);                                      \
    const float G_ = ftanh(v2 + bG##I);                                     \
    const float O_ = fsig(v3 + bO##I);                                      \
    cst##I = fmaf(F_, cst##I, I_ * G_);                                     \
    const float hv = O_ * ftanh(cst##I);                                    \
    hl##I = hv;                                                             \
    wsplit(&s_ah[nb][m][KH0 + c], &s_al[nb][m][KH0 + c], hv);               \
    if (WRITE_H && c < Hn)                                                  \
      hout[((size_t)t * Bn + eb + m) * Hn + c] = hv;                        \
  }

template <bool FIRST, bool WRITE_H, bool DO_FC>
__global__ __launch_bounds__(256, 1) void lstm_step(
    const float* xin,                 // FIRST: x[B][T]; else prev hseq [T][B][H]
    const float* __restrict__ wih,    // FIRST: [4H][1]; else [4H][H]
    const float* __restrict__ whh,    // [4H][H]
    const float* __restrict__ bias,   // [4H]
    float* hout,                      // [T][B][H]
    const float* __restrict__ wfc,    // [H]
    const float* __restrict__ bfc,    // [1]
    float* __restrict__ out)          // [B]
{
  constexpr int NC  = FIRST ? 2 : 4;   // K chunks of 32
  constexpr int KH0 = FIRST ? 1 : 50;  // k offset of h region

  __shared__ __align__(16) short s_ah[2][16][RS];  // A hi, double-buffered
  __shared__ __align__(16) short s_al[2][16][RS];  // A lo
  __shared__ float s_fc[4][16];

  const int tid  = threadIdx.x;
  const int w    = tid >> 6;
  const int lane = tid & 63;
  const int quad = lane >> 4;
  const int nl   = lane & 15;
  const int jj   = nl >> 2;            // cell-sub within tile
  const int ss   = nl & 3;             // gate index (B) / elem-sub (after T)
  const int m    = quad * 4 + ss;      // elem this lane cell-updates
  const int eb   = blockIdx.x * 16;
  const int tl0 = w, tl1 = w + 4, tl2 = w + 8, tl3 = w + 12;
  const int mu = tid & 15, gu = tid >> 4;  // x-staging mapping

  // ---- persistent B-fragments (AGPR-resident; MFMA-direct operands) ----
  short8 bh00 = {0}, bh01 = {0}, bh02 = {0}, bh03 = {0};
  short8 bh10 = {0}, bh11 = {0}, bh12 = {0}, bh13 = {0};
  short8 bh20 = {0}, bh21 = {0}, bh22 = {0}, bh23 = {0};
  short8 bh30 = {0}, bh31 = {0}, bh32 = {0}, bh33 = {0};
  short8 bl00 = {0}, bl01 = {0}, bl02 = {0}, bl03 = {0};
  short8 bl10 = {0}, bl11 = {0}, bl12 = {0}, bl13 = {0};
  short8 bl20 = {0}, bl21 = {0}, bl22 = {0}, bl23 = {0};
  short8 bl30 = {0}, bl31 = {0}, bl32 = {0}, bl33 = {0};
  LOADB(0, 0) LOADB(0, 1) LOADB(0, 2) LOADB(0, 3)
  LOADB(1, 0) LOADB(1, 1) LOADB(1, 2) LOADB(1, 3)
  LOADB(2, 0) LOADB(2, 1) LOADB(2, 2) LOADB(2, 3)
  LOADB(3, 0) LOADB(3, 1) LOADB(3, 2) LOADB(3, 3)
  BIASLD(0) BIASLD(1) BIASLD(2) BIASLD(3)

  float cst0 = 0.f, cst1 = 0.f, cst2 = 0.f, cst3 = 0.f;
  float hl0 = 0.f, hl1 = 0.f, hl2 = 0.f, hl3 = 0.f;

  // ---- zero both A-plane buffers (h0=0, pad-K=0 -> no NaN into MFMA) ----
  for (int i = tid; i < 2 * 16 * RS; i += 256) {
    (&s_ah[0][0][0])[i] = 0;
    (&s_al[0][0][0])[i] = 0;
  }
  __syncthreads();
  // ---- stage x(0) into buffer 0 ----
  if (FIRST) {
    if (tid < 16) {
      const float xv = xin[(size_t)(eb + tid) * Tn + 0];
      wsplit(&s_ah[0][tid][0], &s_al[0][tid][0], xv);
    }
  } else {
#pragma unroll
    for (int r = 0; r < 4; ++r) {
      const int k = gu + 16 * r;
      if (k < Hn) {
        const float xv = xin[((size_t)0 * Bn + eb + mu) * Hn + k];
        wsplit(&s_ah[0][mu][k], &s_al[0][mu][k], xv);
      }
    }
  }
  __syncthreads();

#pragma unroll 1
  for (int t = 0; t < Tn; ++t) {
    const int pb = t & 1, nb = pb ^ 1;
    const int tn = (t + 1 < Tn) ? t + 1 : t;

    // issue x(t+1) loads first (drained by the barrier at step end)
    float xq0 = 0.f, xq1 = 0.f, xq2 = 0.f, xq3 = 0.f;
    if (FIRST) {
      if (tid < 16) xq0 = xin[(size_t)(eb + tid) * Tn + tn];
    } else {
      const float* xrow = xin + ((size_t)tn * Bn + eb + mu) * Hn;
      xq0 = xrow[gu];
      xq1 = xrow[gu + 16];
      xq2 = xrow[gu + 32];
      if (gu + 48 < Hn) xq3 = xrow[gu + 48];
    }

    // A fragments for this step (m = nl, k = chunk*32 + quad*8 + j)
    short8 ah2 = {0}, ah3 = {0}, aL2 = {0}, aL3 = {0};
    const short8 ah0 = *(const short8*)&s_ah[pb][nl][0 * 32 + quad * 8];
    const short8 aL0 = *(const short8*)&s_al[pb][nl][0 * 32 + quad * 8];
    const short8 ah1 = *(const short8*)&s_ah[pb][nl][1 * 32 + quad * 8];
    const short8 aL1 = *(const short8*)&s_al[pb][nl][1 * 32 + quad * 8];
    if (NC > 2) {
      ah2 = *(const short8*)&s_ah[pb][nl][2 * 32 + quad * 8];
      aL2 = *(const short8*)&s_al[pb][nl][2 * 32 + quad * 8];
      ah3 = *(const short8*)&s_ah[pb][nl][3 * 32 + quad * 8];
      aL3 = *(const short8*)&s_al[pb][nl][3 * 32 + quad * 8];
    }

    TILE_STEP(0)
    TILE_STEP(1)
    TILE_STEP(2)
    TILE_STEP(3)

    // stage x(t+1) into next buffer
    if (FIRST) {
      if (tid < 16) wsplit(&s_ah[nb][tid][0], &s_al[nb][tid][0], xq0);
    } else {
      wsplit(&s_ah[nb][mu][gu], &s_al[nb][mu][gu], xq0);
      wsplit(&s_ah[nb][mu][gu + 16], &s_al[nb][mu][gu + 16], xq1);
      wsplit(&s_ah[nb][mu][gu + 32], &s_al[nb][mu][gu + 32], xq2);
      if (gu + 48 < Hn)
        wsplit(&s_ah[nb][mu][gu + 48], &s_al[nb][mu][gu + 48], xq3);
    }

    __syncthreads();  // the ONE barrier per step
  }

  if (DO_FC) {
    float p = 0.f;
    if (tl0 < 13) { const int c = 4 * tl0 + jj; if (c < Hn) p += hl0 * wfc[c]; }
    if (tl1 < 13) { const int c = 4 * tl1 + jj; if (c < Hn) p += hl1 * wfc[c]; }
    if (tl2 < 13) { const int c = 4 * tl2 + jj; if (c < Hn) p += hl2 * wfc[c]; }
    if (tl3 < 13) { const int c = 4 * tl3 + jj; if (c < Hn) p += hl3 * wfc[c]; }
    p += __shfl_xor(p, 4);   // sum the 4 jj-lanes holding the same elem
    p += __shfl_xor(p, 8);
    if (jj == 0) s_fc[w][m] = p;
    __syncthreads();
    if (tid < 16) {
      out[eb + tid] =
          bfc[0] + s_fc[0][tid] + s_fc[1][tid] + s_fc[2][tid] + s_fc[3][tid];
    }
  }
}

}  // namespace

extern "C" void kernel_launch(void* const* d_in, const int* in_sizes, int n_in,
                              void* d_out, int out_size, void* d_ws, size_t ws_size,
                              hipStream_t stream) {
  const float* x    = (const float*)d_in[0];
  const float* wih1 = (const float*)d_in[1];
  const float* whh1 = (const float*)d_in[2];
  const float* b1   = (const float*)d_in[3];
  const float* wih2 = (const float*)d_in[4];
  const float* whh2 = (const float*)d_in[5];
  const float* b2   = (const float*)d_in[6];
  const float* wih3 = (const float*)d_in[7];
  const float* whh3 = (const float*)d_in[8];
  const float* b3   = (const float*)d_in[9];
  const float* wfc  = (const float*)d_in[10];
  const float* bfc  = (const float*)d_in[11];
  float* out = (float*)d_out;

  float* buf = (float*)d_ws;  // hseq fp32 [T][B][H] = 200 MiB (fits; R1-R5)

  dim3 grid(Bn / 16), blk(256);  // 128 blocks x 4 waves, 16 elems/block
  lstm_step<true, true, false><<<grid, blk, 0, stream>>>(
      x, wih1, whh1, b1, buf, nullptr, nullptr, nullptr);
  lstm_step<false, true, false><<<grid, blk, 0, stream>>>(
      buf, wih2, whh2, b2, buf, nullptr, nullptr, nullptr);
  lstm_step<false, false, true><<<grid, blk, 0, stream>>>(
      buf, wih3, whh3, b3, nullptr, wfc, bfc, out);
}

// Round 7
// 1746.967 us; speedup vs baseline: 1.6770x; 1.6770x over previous
//
#include <hip/hip_runtime.h>

namespace {

constexpr int Hn = 50;    // hidden size
constexpr int Bn = 2048;  // batch
constexpr int Tn = 512;   // sequence length
constexpr int S1 = 88;    // P1 row stride (shorts): 44 words = 12 mod 32
constexpr int S2 = 152;   // P2/P3 row stride (shorts): 76 words = 12 mod 32

typedef short short8 __attribute__((ext_vector_type(8)));
typedef float f32x4 __attribute__((ext_vector_type(4)));

__device__ __forceinline__ unsigned bcu(float f) { return __builtin_bit_cast(unsigned, f); }
__device__ __forceinline__ float bcf(unsigned u) { return __builtin_bit_cast(float, u); }

__device__ __forceinline__ float fsig(float x) {
  return 1.0f / (1.0f + __expf(-x));  // x<<0 -> exp=inf -> 0 : safe
}
__device__ __forceinline__ float ftanh(float x) {
  float a = fabsf(x);
  float e = __expf(-2.0f * a);        // in (0,1]
  float t = (1.0f - e) / (1.0f + e);
  return copysignf(t, x);
}
__device__ __forceinline__ void wsplit(short* ph, short* pl, float v) {
  const unsigned u = bcu(v);
  *ph = (short)(u >> 16);
  *pl = (short)(bcu(v - bcf(u & 0xFFFF0000u)) >> 16);
}

#define MF(a, b, c) __builtin_amdgcn_mfma_f32_16x16x32_bf16(a, b, c, 0, 0, 0)

// ============================================================================
// FUSED 3-layer LSTM + FC, systolic in time. One kernel, 128 blocks x 512 thr
// (8 waves = l1:2, l2:3, l3:3), 16 batch elems/block. Iteration i: l1 does
// step i, l2 step i-1, l3 step i-2 -> every h consumed was produced exactly
// one iteration earlier -> double-buffered LDS u-planes, ONE barrier/iter,
// ZERO inter-layer global traffic (no hseq!). Global in loop: only l1's 16
// x-floats/iter. Weights are the A-operand (rows permuted n=16t+4c+g), so
// D gives each lane all 4 gates of one (cell,elem) in its 4 acc regs ->
// cell update straight from registers, no transpose, no exchange.
// u is the B-operand staged k-major per elem row (n=lane&15, k=quad*8+j).
// fp32 accuracy via 3-term split-bf16 (Wh*Uh + Wl*Uh + Wh*Ul), bias as the
// MFMA C-init. Weight frags are MFMA operands -> VGPR/AGPR-resident, immune
// to the R1-R4 demotion/spill pathology.
// Planes: P1=[x|h1] K=64; P2=[h1|h2] K=128; P3=[h2|h3] K=128 (pads zero).
// ============================================================================

// declare + load one weight fragment pair (hi/lo), meaning depends on layer L
#define LW(FI)                                                               \
  short8 FH##FI = {0, 0, 0, 0, 0, 0, 0, 0};                                  \
  short8 FL##FI = {0, 0, 0, 0, 0, 0, 0, 0};                                  \
  {                                                                          \
    const int tile_ = (L == 0) ? (wl + 2 * ((FI) >> 1))                      \
                               : (wl + 3 * ((FI) >> 2));                     \
    const int chunk_ = (L == 0) ? ((FI)&1) : ((FI)&3);                       \
    const int cb_ = 4 * tile_ + (nl >> 2);                                   \
    if (tile_ < 13 && cb_ < Hn) {                                            \
      const int row_ = (nl & 3) * Hn + cb_;                                  \
      _Pragma("unroll") for (int jj = 0; jj < 8; ++jj) {                     \
        const int k_ = 32 * chunk_ + quad * 8 + jj;                          \
        float wv = 0.f;                                                      \
        if (L == 0) {                                                        \
          if (k_ == 0) wv = wihL[row_];                                      \
          else if (k_ <= Hn) wv = whhL[row_ * Hn + k_ - 1];                  \
        } else {                                                             \
          if (k_ < Hn) wv = wihL[row_ * Hn + k_];                            \
          else if (k_ < 2 * Hn) wv = whhL[row_ * Hn + k_ - Hn];              \
        }                                                                    \
        const unsigned uu = bcu(wv);                                         \
        FH##FI[jj] = (short)(uu >> 16);                                      \
        FL##FI[jj] = (short)(bcu(wv - bcf(uu & 0xFFFF0000u)) >> 16);         \
      }                                                                      \
    }                                                                        \
  }

#define BINIT(J)                                                             \
  const int tile##J =                                                        \
      (L == 0) ? (wl + 2 * (J)) : ((J) < 5 ? (wl + 3 * (J)) : 13);           \
  const int tv##J = tile##J < 13;                                            \
  const int cell##J = 4 * tile##J + quad;                                    \
  f32x4 bv##J = {0.f, 0.f, 0.f, 0.f};                                        \
  if (tv##J && cell##J < Hn) {                                               \
    bv##J[0] = biasL[cell##J];                                               \
    bv##J[1] = biasL[Hn + cell##J];                                          \
    bv##J[2] = biasL[2 * Hn + cell##J];                                      \
    bv##J[3] = biasL[3 * Hn + cell##J];                                      \
  }                                                                          \
  float cs##J = 0.f, hl##J = 0.f;

// 3-term split-bf16 MFMA for tile J with fragment FI (weights = A, u = B)
#define MTM(J, FI)                                                           \
  if (tv##J) {                                                               \
    ac##J = MF(FH##FI, uh_, ac##J);                                          \
    ac##J = MF(FL##FI, uh_, ac##J);                                          \
    ac##J = MF(FH##FI, ul_, ac##J);                                          \
  }

#define MCH5(PH, PL, C, F0, F1, F2, F3, F4)                                  \
  {                                                                          \
    const short8 uh_ = *(const short8*)&PH[rb][nl][32 * (C) + quad * 8];     \
    const short8 ul_ = *(const short8*)&PL[rb][nl][32 * (C) + quad * 8];     \
    MTM(0, F0) MTM(1, F1) MTM(2, F2) MTM(3, F3) MTM(4, F4)                   \
  }

#define MCH7(C, F0, F1, F2, F3, F4, F5, F6)                                  \
  {                                                                          \
    const short8 uh_ = *(const short8*)&p1h[rb][nl][32 * (C) + quad * 8];    \
    const short8 ul_ = *(const short8*)&p1l[rb][nl][32 * (C) + quad * 8];    \
    MTM(0, F0) MTM(1, F1) MTM(2, F2) MTM(3, F3) MTM(4, F4) MTM(5, F5)        \
    MTM(6, F6)                                                               \
  }

// cell update for tile J; write h to own-plane (OH/OL at KO) and optionally
// the next layer's plane (O2H/O2L at K2)
#define CUP(J, OH, OL, KO, DO2, O2H, O2L, K2)                                \
  if (tv##J) {                                                               \
    const float I_ = fsig(ac##J[0]);                                         \
    const float F_ = fsig(ac##J[1]);                                         \
    const float G_ = ftanh(ac##J[2]);                                        \
    const float O_ = fsig(ac##J[3]);                                         \
    cs##J = fmaf(F_, cs##J, I_ * G_);                                        \
    const float hv = O_ * ftanh(cs##J);                                      \
    hl##J = hv;                                                              \
    if (cell##J < Hn) {                                                      \
      wsplit(&OH[wb][nl][(KO) + cell##J], &OL[wb][nl][(KO) + cell##J], hv);  \
      if (DO2)                                                               \
        wsplit(&O2H[wb][nl][(K2) + cell##J], &O2L[wb][nl][(K2) + cell##J],   \
               hv);                                                          \
    }                                                                        \
  }

__global__ __launch_bounds__(512, 2) void lstm_fused(
    const float* __restrict__ xg,    // [B][T]
    const float* __restrict__ wih1, const float* __restrict__ whh1,
    const float* __restrict__ b1, const float* __restrict__ wih2,
    const float* __restrict__ whh2, const float* __restrict__ b2,
    const float* __restrict__ wih3, const float* __restrict__ whh3,
    const float* __restrict__ b3, const float* __restrict__ wfc,
    const float* __restrict__ bfc, float* __restrict__ out)  // [B]
{
  __shared__ __align__(16) short p1h[2][16][S1];
  __shared__ __align__(16) short p1l[2][16][S1];
  __shared__ __align__(16) short p2h[2][16][S2];
  __shared__ __align__(16) short p2l[2][16][S2];
  __shared__ __align__(16) short p3h[2][16][S2];
  __shared__ __align__(16) short p3l[2][16][S2];
  __shared__ float s_fc[3][16];

  const int tid = threadIdx.x;
  const int w = tid >> 6;
  const int lane = tid & 63;
  const int quad = lane >> 4;
  const int nl = lane & 15;
  const int L = (w < 2) ? 0 : (w < 5) ? 1 : 2;       // layer of this wave
  const int wl = w - (L == 0 ? 0 : (L == 1 ? 2 : 5));  // wave idx within layer
  const int eb = blockIdx.x * 16;

  const float* wihL = (L == 0) ? wih1 : (L == 1) ? wih2 : wih3;
  const float* whhL = (L == 0) ? whh1 : (L == 1) ? whh2 : whh3;
  const float* biasL = (L == 0) ? b1 : (L == 1) ? b2 : b3;

  // ---- persistent weight fragments (20 hi + 20 lo; l1 uses f<14) ----
  LW(0) LW(1) LW(2) LW(3) LW(4) LW(5) LW(6) LW(7) LW(8) LW(9)
  LW(10) LW(11) LW(12) LW(13) LW(14) LW(15) LW(16) LW(17) LW(18) LW(19)

  BINIT(0) BINIT(1) BINIT(2) BINIT(3) BINIT(4) BINIT(5) BINIT(6)

  // ---- zero all planes, both buffers (h(-1)=0, K-pads=0) ----
  for (int i = tid; i < 2 * 16 * S1; i += 512) {
    (&p1h[0][0][0])[i] = 0;
    (&p1l[0][0][0])[i] = 0;
  }
  for (int i = tid; i < 2 * 16 * S2; i += 512) {
    (&p2h[0][0][0])[i] = 0;
    (&p2l[0][0][0])[i] = 0;
    (&p3h[0][0][0])[i] = 0;
    (&p3l[0][0][0])[i] = 0;
  }
  __syncthreads();
  if (w == 0 && lane < 16) {
    const float xv = xg[(size_t)(eb + lane) * Tn + 0];
    wsplit(&p1h[0][lane][0], &p1l[0][lane][0], xv);
  }
  __syncthreads();

#pragma unroll 1
  for (int i = 0; i < Tn + 2; ++i) {
    const int rb = i & 1, wb = rb ^ 1;
    if (L == 0) {
      if (i < Tn) {
        float xv = 0.f;
        if (w == 0 && lane < 16 && i + 1 < Tn)
          xv = xg[(size_t)(eb + lane) * Tn + (i + 1)];
        f32x4 ac0 = bv0, ac1 = bv1, ac2 = bv2, ac3 = bv3, ac4 = bv4,
              ac5 = bv5, ac6 = bv6;
        MCH7(0, 0, 2, 4, 6, 8, 10, 12)
        MCH7(1, 1, 3, 5, 7, 9, 11, 13)
        CUP(0, p1h, p1l, 1, 1, p2h, p2l, 0)
        CUP(1, p1h, p1l, 1, 1, p2h, p2l, 0)
        CUP(2, p1h, p1l, 1, 1, p2h, p2l, 0)
        CUP(3, p1h, p1l, 1, 1, p2h, p2l, 0)
        CUP(4, p1h, p1l, 1, 1, p2h, p2l, 0)
        CUP(5, p1h, p1l, 1, 1, p2h, p2l, 0)
        CUP(6, p1h, p1l, 1, 1, p2h, p2l, 0)
        if (w == 0 && lane < 16)
          wsplit(&p1h[wb][lane][0], &p1l[wb][lane][0], xv);
      }
    } else if (L == 1) {
      if (i >= 1 && i <= Tn) {
        f32x4 ac0 = bv0, ac1 = bv1, ac2 = bv2, ac3 = bv3, ac4 = bv4;
        MCH5(p2h, p2l, 0, 0, 4, 8, 12, 16)
        MCH5(p2h, p2l, 1, 1, 5, 9, 13, 17)
        MCH5(p2h, p2l, 2, 2, 6, 10, 14, 18)
        MCH5(p2h, p2l, 3, 3, 7, 11, 15, 19)
        CUP(0, p2h, p2l, Hn, 1, p3h, p3l, 0)
        CUP(1, p2h, p2l, Hn, 1, p3h, p3l, 0)
        CUP(2, p2h, p2l, Hn, 1, p3h, p3l, 0)
        CUP(3, p2h, p2l, Hn, 1, p3h, p3l, 0)
        CUP(4, p2h, p2l, Hn, 1, p3h, p3l, 0)
      }
    } else {
      if (i >= 2) {
        f32x4 ac0 = bv0, ac1 = bv1, ac2 = bv2, ac3 = bv3, ac4 = bv4;
        MCH5(p3h, p3l, 0, 0, 4, 8, 12, 16)
        MCH5(p3h, p3l, 1, 1, 5, 9, 13, 17)
        MCH5(p3h, p3l, 2, 2, 6, 10, 14, 18)
        MCH5(p3h, p3l, 3, 3, 7, 11, 15, 19)
        CUP(0, p3h, p3l, Hn, 0, p3h, p3l, 0)
        CUP(1, p3h, p3l, Hn, 0, p3h, p3l, 0)
        CUP(2, p3h, p3l, Hn, 0, p3h, p3l, 0)
        CUP(3, p3h, p3l, Hn, 0, p3h, p3l, 0)
        CUP(4, p3h, p3l, Hn, 0, p3h, p3l, 0)
      }
    }
    __syncthreads();
  }

  // ---- FC on h3(T-1), held in l3 waves' hl registers ----
  if (L == 2) {
    float pfc = 0.f;
    if (tv0 && cell0 < Hn) pfc += hl0 * wfc[cell0];
    if (tv1 && cell1 < Hn) pfc += hl1 * wfc[cell1];
    if (tv2 && cell2 < Hn) pfc += hl2 * wfc[cell2];
    if (tv3 && cell3 < Hn) pfc += hl3 * wfc[cell3];
    if (tv4 && cell4 < Hn) pfc += hl4 * wfc[cell4];
    pfc += __shfl_xor(pfc, 16);  // sum over the 4 quads (cells)
    pfc += __shfl_xor(pfc, 32);
    if (lane < 16) s_fc[wl][lane] = pfc;
  }
  __syncthreads();
  if (tid < 16)
    out[eb + tid] = bfc[0] + s_fc[0][tid] + s_fc[1][tid] + s_fc[2][tid];
}

}  // namespace

extern "C" void kernel_launch(void* const* d_in, const int* in_sizes, int n_in,
                              void* d_out, int out_size, void* d_ws, size_t ws_size,
                              hipStream_t stream) {
  const float* x    = (const float*)d_in[0];
  const float* wih1 = (const float*)d_in[1];
  const float* whh1 = (const float*)d_in[2];
  const float* b1   = (const float*)d_in[3];
  const float* wih2 = (const float*)d_in[4];
  const float* whh2 = (const float*)d_in[5];
  const float* b2   = (const float*)d_in[6];
  const float* wih3 = (const float*)d_in[7];
  const float* whh3 = (const float*)d_in[8];
  const float* b3   = (const float*)d_in[9];
  const float* wfc  = (const float*)d_in[10];
  const float* bfc  = (const float*)d_in[11];
  float* out = (float*)d_out;

  lstm_fused<<<dim3(Bn / 16), dim3(512), 0, stream>>>(
      x, wih1, whh1, b1, wih2, whh2, b2, wih3, whh3, b3, wfc, bfc, out);
}

// Round 8
// 1542.512 us; speedup vs baseline: 1.8992x; 1.1325x over previous
//
#include <hip/hip_runtime.h>

namespace {

constexpr int Hn = 50;    // hidden size
constexpr int Bn = 2048;  // batch
constexpr int Tn = 512;   // sequence length
constexpr int SW = 72;    // plane row stride in shorts (144 B: 16B-slot stride 16 mod 128 -> 2-way = free)

typedef short short8 __attribute__((ext_vector_type(8)));
typedef float f32x4 __attribute__((ext_vector_type(4)));

__device__ __forceinline__ unsigned bcu(float f) { return __builtin_bit_cast(unsigned, f); }
__device__ __forceinline__ float bcf(unsigned u) { return __builtin_bit_cast(float, u); }
__device__ __forceinline__ float rcpa(float x) { return __builtin_amdgcn_rcpf(x); }

// v_rcp-based activations: ~1e-7 rel err, ~4x fewer VALU ops than precise-div
__device__ __forceinline__ float fsig(float x) {
  return rcpa(1.0f + __expf(-x));      // x<<0 -> exp=inf -> rcp(inf)=0 : safe
}
__device__ __forceinline__ float ftanh(float x) {
  const float a = fabsf(x);
  const float e = __expf(-2.0f * a);   // in (0,1]
  const float t = (1.0f - e) * rcpa(1.0f + e);
  return copysignf(t, x);
}
__device__ __forceinline__ void wsplit(short* ph, short* pl, float v) {
  const unsigned u = bcu(v);
  *ph = (short)(u >> 16);
  *pl = (short)(bcu(v - bcf(u & 0xFFFF0000u)) >> 16);
}

#define MF(a, b, c) __builtin_amdgcn_mfma_f32_16x16x32_bf16(a, b, c, 0, 0, 0)

// ============================================================================
// FUSED 3-layer LSTM + FC, systolic in time (R7 skeleton). 128 blocks x 512
// thr (8 waves = l1:2, l2:3, l3:3), 16 elems/block, ONE barrier/iter.
// R8 changes (attack the VALU-throughput wall):
//  - rcp-based sigmoid/tanh (no precise-div expansion).
//  - SINGLE h-write: l2's W_ih fragments are k-mapped to read h1 directly
//    from l1's plane (x slot gets zero weight -> exact), l3 reads h2 from
//    l2's plane. Planes all K=64: P1=[x,h1(k=1..50)], P2=[h2(k=0..49)],
//    P3=[h3(k=0..49)]; l2 consumes chunks {P1:0,1, P2:0,1} with combined
//    weight k = {0..63, 64..127}; same for l3 on {P2,P3}.
//  - stride 72 shorts: b128 reads uniform over banks (2-way only = free).
// fp32 accuracy via 3-term split-bf16 (Wh*Uh + Wl*Uh + Wh*Ul); bias as
// MFMA C-init; weight frags = MFMA operands (reg-resident, R5-R7 verified).
// ============================================================================

#define LW(FI)                                                               \
  short8 FH##FI = {0, 0, 0, 0, 0, 0, 0, 0};                                  \
  short8 FL##FI = {0, 0, 0, 0, 0, 0, 0, 0};                                  \
  {                                                                          \
    const int tile_ = (L == 0) ? (wl + 2 * ((FI) >> 1))                      \
                               : (wl + 3 * ((FI) >> 2));                     \
    const int chunk_ = (L == 0) ? ((FI)&1) : ((FI)&3);                       \
    const int cb_ = 4 * tile_ + (nl >> 2);                                   \
    if (tile_ < 13 && cb_ < Hn) {                                            \
      const int row_ = (nl & 3) * Hn + cb_;                                  \
      _Pragma("unroll") for (int jj = 0; jj < 8; ++jj) {                     \
        const int k_ = 32 * chunk_ + quad * 8 + jj;                          \
        float wv = 0.f;                                                      \
        if (L == 0) {                                                        \
          if (k_ == 0) wv = wihL[row_];                                      \
          else if (k_ <= Hn) wv = whhL[row_ * Hn + k_ - 1];                  \
        } else if (L == 1) {                                                 \
          if (k_ >= 1 && k_ <= Hn) wv = wihL[row_ * Hn + k_ - 1];            \
          else if (k_ >= 64 && k_ < 64 + Hn) wv = whhL[row_ * Hn + k_ - 64]; \
        } else {                                                             \
          if (k_ < Hn) wv = wihL[row_ * Hn + k_];                            \
          else if (k_ >= 64 && k_ < 64 + Hn) wv = whhL[row_ * Hn + k_ - 64]; \
        }                                                                    \
        const unsigned uu = bcu(wv);                                         \
        FH##FI[jj] = (short)(uu >> 16);                                      \
        FL##FI[jj] = (short)(bcu(wv - bcf(uu & 0xFFFF0000u)) >> 16);         \
      }                                                                      \
    }                                                                        \
  }

#define BINIT(J)                                                             \
  const int tile##J =                                                        \
      (L == 0) ? (wl + 2 * (J)) : ((J) < 5 ? (wl + 3 * (J)) : 13);           \
  const int tv##J = tile##J < 13;                                            \
  const int cell##J = 4 * tile##J + quad;                                    \
  f32x4 bv##J = {0.f, 0.f, 0.f, 0.f};                                        \
  if (tv##J && cell##J < Hn) {                                               \
    bv##J[0] = biasL[cell##J];                                               \
    bv##J[1] = biasL[Hn + cell##J];                                          \
    bv##J[2] = biasL[2 * Hn + cell##J];                                      \
    bv##J[3] = biasL[3 * Hn + cell##J];                                      \
  }                                                                          \
  float cs##J = 0.f, hl##J = 0.f;

#define MTM(J, FI)                                                           \
  if (tv##J) {                                                               \
    ac##J = MF(FH##FI, uh_, ac##J);                                          \
    ac##J = MF(FL##FI, uh_, ac##J);                                          \
    ac##J = MF(FH##FI, ul_, ac##J);                                          \
  }

// LC = chunk offset within the source plane (0 or 1)
#define MCH5(PH, PL, LC, F0, F1, F2, F3, F4)                                 \
  {                                                                          \
    const short8 uh_ = *(const short8*)&PH[rb][nl][32 * (LC) + quad * 8];    \
    const short8 ul_ = *(const short8*)&PL[rb][nl][32 * (LC) + quad * 8];    \
    MTM(0, F0) MTM(1, F1) MTM(2, F2) MTM(3, F3) MTM(4, F4)                   \
  }

#define MCH7(LC, F0, F1, F2, F3, F4, F5, F6)                                 \
  {                                                                          \
    const short8 uh_ = *(const short8*)&p1h[rb][nl][32 * (LC) + quad * 8];   \
    const short8 ul_ = *(const short8*)&p1l[rb][nl][32 * (LC) + quad * 8];   \
    MTM(0, F0) MTM(1, F1) MTM(2, F2) MTM(3, F3) MTM(4, F4) MTM(5, F5)        \
    MTM(6, F6)                                                               \
  }

// cell update for tile J; SINGLE h write into plane (PH,PL) at k = KO+cell
#define CUP(J, PH, PL, KO)                                                   \
  if (tv##J) {                                                               \
    const float I_ = fsig(ac##J[0]);                                         \
    const float F_ = fsig(ac##J[1]);                                         \
    const float G_ = ftanh(ac##J[2]);                                        \
    const float O_ = fsig(ac##J[3]);                                         \
    cs##J = fmaf(F_, cs##J, I_ * G_);                                        \
    const float hv = O_ * ftanh(cs##J);                                      \
    hl##J = hv;                                                              \
    if (cell##J < Hn)                                                        \
      wsplit(&PH[wb][nl][(KO) + cell##J], &PL[wb][nl][(KO) + cell##J], hv);  \
  }

__global__ __launch_bounds__(512, 2) void lstm_fused(
    const float* __restrict__ xg,    // [B][T]
    const float* __restrict__ wih1, const float* __restrict__ whh1,
    const float* __restrict__ b1, const float* __restrict__ wih2,
    const float* __restrict__ whh2, const float* __restrict__ b2,
    const float* __restrict__ wih3, const float* __restrict__ whh3,
    const float* __restrict__ b3, const float* __restrict__ wfc,
    const float* __restrict__ bfc, float* __restrict__ out)  // [B]
{
  __shared__ __align__(16) short p1h[2][16][SW];  // [x | h1(1..50)]
  __shared__ __align__(16) short p1l[2][16][SW];
  __shared__ __align__(16) short p2h[2][16][SW];  // [h2(0..49)]
  __shared__ __align__(16) short p2l[2][16][SW];
  __shared__ __align__(16) short p3h[2][16][SW];  // [h3(0..49)]
  __shared__ __align__(16) short p3l[2][16][SW];
  __shared__ float s_fc[3][16];

  const int tid = threadIdx.x;
  const int w = tid >> 6;
  const int lane = tid & 63;
  const int quad = lane >> 4;
  const int nl = lane & 15;
  const int L = (w < 2) ? 0 : (w < 5) ? 1 : 2;
  const int wl = w - (L == 0 ? 0 : (L == 1 ? 2 : 5));
  const int eb = blockIdx.x * 16;

  const float* wihL = (L == 0) ? wih1 : (L == 1) ? wih2 : wih3;
  const float* whhL = (L == 0) ? whh1 : (L == 1) ? whh2 : whh3;
  const float* biasL = (L == 0) ? b1 : (L == 1) ? b2 : b3;

  LW(0) LW(1) LW(2) LW(3) LW(4) LW(5) LW(6) LW(7) LW(8) LW(9)
  LW(10) LW(11) LW(12) LW(13) LW(14) LW(15) LW(16) LW(17) LW(18) LW(19)

  BINIT(0) BINIT(1) BINIT(2) BINIT(3) BINIT(4) BINIT(5) BINIT(6)

  for (int i = tid; i < 2 * 16 * SW; i += 512) {
    (&p1h[0][0][0])[i] = 0;
    (&p1l[0][0][0])[i] = 0;
    (&p2h[0][0][0])[i] = 0;
    (&p2l[0][0][0])[i] = 0;
    (&p3h[0][0][0])[i] = 0;
    (&p3l[0][0][0])[i] = 0;
  }
  __syncthreads();
  if (w == 0 && lane < 16) {
    const float xv = xg[(size_t)(eb + lane) * Tn + 0];
    wsplit(&p1h[0][lane][0], &p1l[0][lane][0], xv);
  }
  __syncthreads();

#pragma unroll 1
  for (int i = 0; i < Tn + 2; ++i) {
    const int rb = i & 1, wb = rb ^ 1;
    if (L == 0) {
      if (i < Tn) {
        float xv = 0.f;
        if (w == 0 && lane < 16 && i + 1 < Tn)
          xv = xg[(size_t)(eb + lane) * Tn + (i + 1)];
        f32x4 ac0 = bv0, ac1 = bv1, ac2 = bv2, ac3 = bv3, ac4 = bv4,
              ac5 = bv5, ac6 = bv6;
        MCH7(0, 0, 2, 4, 6, 8, 10, 12)
        MCH7(1, 1, 3, 5, 7, 9, 11, 13)
        CUP(0, p1h, p1l, 1)
        CUP(1, p1h, p1l, 1)
        CUP(2, p1h, p1l, 1)
        CUP(3, p1h, p1l, 1)
        CUP(4, p1h, p1l, 1)
        CUP(5, p1h, p1l, 1)
        CUP(6, p1h, p1l, 1)
        if (w == 0 && lane < 16)
          wsplit(&p1h[wb][lane][0], &p1l[wb][lane][0], xv);
      }
    } else if (L == 1) {
      if (i >= 1 && i <= Tn) {
        f32x4 ac0 = bv0, ac1 = bv1, ac2 = bv2, ac3 = bv3, ac4 = bv4;
        MCH5(p1h, p1l, 0, 0, 4, 8, 12, 16)    // combined k 0..31  (h1)
        MCH5(p1h, p1l, 1, 1, 5, 9, 13, 17)    // combined k 32..63 (h1)
        MCH5(p2h, p2l, 0, 2, 6, 10, 14, 18)   // combined k 64..95 (h2)
        MCH5(p2h, p2l, 1, 3, 7, 11, 15, 19)   // combined k 96..127(h2)
        CUP(0, p2h, p2l, 0)
        CUP(1, p2h, p2l, 0)
        CUP(2, p2h, p2l, 0)
        CUP(3, p2h, p2l, 0)
        CUP(4, p2h, p2l, 0)
      }
    } else {
      if (i >= 2) {
        f32x4 ac0 = bv0, ac1 = bv1, ac2 = bv2, ac3 = bv3, ac4 = bv4;
        MCH5(p2h, p2l, 0, 0, 4, 8, 12, 16)    // h2
        MCH5(p2h, p2l, 1, 1, 5, 9, 13, 17)
        MCH5(p3h, p3l, 0, 2, 6, 10, 14, 18)   // h3
        MCH5(p3h, p3l, 1, 3, 7, 11, 15, 19)
        CUP(0, p3h, p3l, 0)
        CUP(1, p3h, p3l, 0)
        CUP(2, p3h, p3l, 0)
        CUP(3, p3h, p3l, 0)
        CUP(4, p3h, p3l, 0)
      }
    }
    __syncthreads();
  }

  if (L == 2) {
    float pfc = 0.f;
    if (tv0 && cell0 < Hn) pfc += hl0 * wfc[cell0];
    if (tv1 && cell1 < Hn) pfc += hl1 * wfc[cell1];
    if (tv2 && cell2 < Hn) pfc += hl2 * wfc[cell2];
    if (tv3 && cell3 < Hn) pfc += hl3 * wfc[cell3];
    if (tv4 && cell4 < Hn) pfc += hl4 * wfc[cell4];
    pfc += __shfl_xor(pfc, 16);  // sum over quads (cells)
    pfc += __shfl_xor(pfc, 32);
    if (lane < 16) s_fc[wl][lane] = pfc;
  }
  __syncthreads();
  if (tid < 16)
    out[eb + tid] = bfc[0] + s_fc[0][tid] + s_fc[1][tid] + s_fc[2][tid];
}

}  // namespace

extern "C" void kernel_launch(void* const* d_in, const int* in_sizes, int n_in,
                              void* d_out, int out_size, void* d_ws, size_t ws_size,
                              hipStream_t stream) {
  const float* x    = (const float*)d_in[0];
  const float* wih1 = (const float*)d_in[1];
  const float* whh1 = (const float*)d_in[2];
  const float* b1   = (const float*)d_in[3];
  const float* wih2 = (const float*)d_in[4];
  const float* whh2 = (const float*)d_in[5];
  const float* b2   = (const float*)d_in[6];
  const float* wih3 = (const float*)d_in[7];
  const float* whh3 = (const float*)d_in[8];
  const float* b3   = (const float*)d_in[9];
  const float* wfc  = (const float*)d_in[10];
  const float* bfc  = (const float*)d_in[11];
  float* out = (float*)d_out;

  lstm_fused<<<dim3(Bn / 16), dim3(512), 0, stream>>>(
      x, wih1, whh1, b1, wih2, whh2, b2, wih3, whh3, b3, wfc, bfc, out);
}